// Round 19
// baseline (235.890 us; speedup 1.0000x reference)
//
#include <hip/hip_runtime.h>
#include <cstdint>

typedef __attribute__((ext_vector_type(8))) _Float16 half8;
typedef __attribute__((ext_vector_type(4))) _Float16 half4;
typedef __attribute__((ext_vector_type(4))) float f32x4;

// ---------------- weight prep: fp32 W -> permuted-K fp16 hi/lo A-fragments ----------------
__global__ void prep_weights(const float* __restrict__ cWh, const float* __restrict__ cWo,
                             const float* __restrict__ sWh, const float* __restrict__ sWo,
                             _Float16* __restrict__ wf) {
    int t = blockIdx.x * 256 + threadIdx.x;  // 0..32767
    int e    = t & 7;
    int mt   = (t >> 3) & 3;
    int lane = (t >> 5) & 63;
    int kp   = (t >> 11) & 1;
    int L    = (t >> 12) & 7;
    const float* src = (L < 3)  ? cWh + L * 4096
                     : (L == 3) ? cWo
                     : (L < 7)  ? sWh + (L - 4) * 4096
                     :            sWo;
    int m = mt * 16 + (lane & 15);
    int k = (2 * kp + (e >> 2)) * 16 + 4 * (lane >> 4) + (e & 3);
    float w = src[m * 64 + k];
    _Float16 hi = (_Float16)w;            // RTNE hardware cvt
    _Float16 lo = (_Float16)(w - (float)hi);
    int off = lane * 32 + mt * 8 + e;
    int fi = (L * 2 + kp) * 2;
    wf[fi * 2048 + off]       = hi;
    wf[(fi + 1) * 2048 + off] = lo;
}

template<bool RELU>
__device__ __forceinline__ half8 cvt_frag(f32x4 a, f32x4 b) {
    half8 r;
#pragma unroll
    for (int i = 0; i < 4; ++i) {
        float va = RELU ? fmaxf(a[i], 0.f) : a[i];
        float vb = RELU ? fmaxf(b[i], 0.f) : b[i];
        r[i]     = (_Float16)va;
        r[i + 4] = (_Float16)vb;
    }
    return r;
}

__device__ __forceinline__ void run_layer(const _Float16* __restrict__ wf, int Lid,
                                          const float* __restrict__ bias, int lane, int g4,
                                          const half8 B[2][4], f32x4 acc[4][4]) {
#pragma unroll
    for (int mt = 0; mt < 4; ++mt) {
        f32x4 bb = *(const f32x4*)(bias + mt * 16 + g4);
#pragma unroll
        for (int nt = 0; nt < 4; ++nt) acc[mt][nt] = bb;
    }
#pragma unroll
    for (int kp = 0; kp < 2; ++kp) {
        half8 Ah[4], Al[4];
        const _Float16* p = wf + (Lid * 2 + kp) * 4096 + lane * 32;
#pragma unroll
        for (int mt = 0; mt < 4; ++mt) {
            Ah[mt] = *(const half8*)(p + mt * 8);
            Al[mt] = *(const half8*)(p + 2048 + mt * 8);
        }
#pragma unroll
        for (int nt = 0; nt < 4; ++nt)
#pragma unroll
            for (int mt = 0; mt < 4; ++mt) {
                acc[mt][nt] = __builtin_amdgcn_mfma_f32_16x16x32_f16(Ah[mt], B[kp][nt], acc[mt][nt], 0, 0, 0);
                acc[mt][nt] = __builtin_amdgcn_mfma_f32_16x16x32_f16(Al[mt], B[kp][nt], acc[mt][nt], 0, 0, 0);
            }
    }
}

__device__ __forceinline__ void acc_to_B_relu(const f32x4 acc[4][4], half8 B[2][4]) {
#pragma unroll
    for (int kp = 0; kp < 2; ++kp)
#pragma unroll
        for (int nt = 0; nt < 4; ++nt)
            B[kp][nt] = cvt_frag<true>(acc[2 * kp][nt], acc[2 * kp + 1][nt]);
}

// both MLPs: B0 -> shift (fp16 parked) and log_scale (left in acc)
__device__ __forceinline__ void run_mlps(const _Float16* __restrict__ wf,
                                         const float* __restrict__ cbh, const float* __restrict__ cbo,
                                         const float* __restrict__ sbh, const float* __restrict__ sbo,
                                         int lane, int g4, const half8 B0[2][4],
                                         half4 shp[4][4], f32x4 acc[4][4]) {
    half8 B[2][4];
    run_layer(wf, 0, cbh,       lane, g4, B0, acc);
    acc_to_B_relu(acc, B);
    run_layer(wf, 1, cbh + 64,  lane, g4, B, acc);
    acc_to_B_relu(acc, B);
    run_layer(wf, 2, cbh + 128, lane, g4, B, acc);
    acc_to_B_relu(acc, B);
    run_layer(wf, 3, cbo,       lane, g4, B, acc);
#pragma unroll
    for (int mt = 0; mt < 4; ++mt)
#pragma unroll
        for (int nt = 0; nt < 4; ++nt) {
            half4 s;
#pragma unroll
            for (int i = 0; i < 4; ++i) s[i] = (_Float16)acc[mt][nt][i];
            shp[mt][nt] = s;
        }
    run_layer(wf, 4, sbh,       lane, g4, B0, acc);
    acc_to_B_relu(acc, B);
    run_layer(wf, 5, sbh + 64,  lane, g4, B, acc);
    acc_to_B_relu(acc, B);
    run_layer(wf, 6, sbh + 128, lane, g4, B, acc);
    acc_to_B_relu(acc, B);
    run_layer(wf, 7, sbo,       lane, g4, B, acc);
}

// epilogue: y[:,64:] = x_t(LDS) * exp(clip(ls)) + shift ; logdet = row-sum(ls)
// xts: x_t of row r at xts[r*stride + (base16 + ((mt*4+g)^(r&7)))*4]
__device__ __forceinline__ void epilogue(const f32x4 acc[4][4], const half4 shp[4][4],
                                         const float* xts, int xstride, int xbase,
                                         float* __restrict__ yr, float* __restrict__ logdet,
                                         long row0, int lane, int c, int g) {
    float pld0 = 0.f, pld1 = 0.f, pld2 = 0.f, pld3 = 0.f;
#pragma unroll
    for (int nt = 0; nt < 4; ++nt) {
        float psum = 0.f;
        const int r = nt * 16 + c;
#pragma unroll
        for (int mt = 0; mt < 4; ++mt) {
            f32x4 ls = acc[mt][nt];
            psum += ls[0] + ls[1] + ls[2] + ls[3];
            const int j = xbase + (((mt * 4 + g) ^ (r & 7)) * 4);
            f32x4 xt = *(const f32x4*)(xts + r * xstride + j);
            half4 sp = shp[mt][nt];
            f32x4 o;
#pragma unroll
            for (int i = 0; i < 4; ++i) {
                float cl = fminf(fmaxf(ls[i], -5.f), 3.f);
                o[i] = xt[i] * __expf(cl) + (float)sp[i];
            }
            *(f32x4*)(yr + nt * 2048 + 64 + mt * 16) = o;
        }
        if (nt == 0) pld0 = psum; else if (nt == 1) pld1 = psum;
        else if (nt == 2) pld2 = psum; else pld3 = psum;
    }
#pragma unroll
    for (int nt = 0; nt < 4; ++nt) {
        float v = (nt == 0) ? pld0 : (nt == 1) ? pld1 : (nt == 2) ? pld2 : pld3;
        v += __shfl_xor(v, 16);
        v += __shfl_xor(v, 32);
        if (g == 0) logdet[row0 + nt * 16 + c] = v;
    }
}

// ---------------- main: 1 wave = 2 tiles x 64 rows; tile1 fully DMA-prefetched in LDS ----------------
__global__ __launch_bounds__(64, 2)
void coupling_main(const float* __restrict__ x,
                   const float* __restrict__ cbh, const float* __restrict__ cbo,
                   const float* __restrict__ sbh, const float* __restrict__ sbo,
                   const _Float16* __restrict__ wf,
                   float* __restrict__ y, float* __restrict__ logdet) {
    __shared__ float xstage0[4096];  // 16 KB: tile0 x_t[64][64], 16B-chunk swizzled by row&7
    __shared__ float xstage1[8192];  // 32 KB: tile1 full x[64][128], 16B-chunk swizzled by row&7
    const int lane = threadIdx.x;
    const int c = lane & 15;
    const int g = lane >> 4;
    const int g4 = g * 4;
    const long row0 = (long)blockIdx.x * 128;   // tile0 rows [row0, row0+64)
    const long row1 = row0 + 64;                // tile1 rows

    // ---- (A) tile0 x_masked register loads (oldest in vmem queue) ----
    const float* xr0 = x + (row0 + c) * 128 + g4;
    float* yr0 = y + (row0 + c) * 128 + g4;
    f32x4 xm[4][4];
#pragma unroll
    for (int nt = 0; nt < 4; ++nt)
#pragma unroll
        for (int kt = 0; kt < 4; ++kt)
            xm[nt][kt] = *(const f32x4*)(xr0 + nt * 2048 + kt * 16);

    // ---- (B) tile0 x_t DMA -> xstage0 (16 x 16B rows-of-4 pattern) ----
    {
        const int rr = lane >> 4;
        const int s  = lane & 15;
#pragma unroll
        for (int i = 0; i < 16; ++i) {
            const int r = i * 4 + rr;
            const int j = s ^ (r & 7);
            const float* src = x + (row0 + r) * 128 + 64 + j * 4;
            __builtin_amdgcn_global_load_lds(
                (const __attribute__((address_space(1))) void*)src,
                (__attribute__((address_space(3))) void*)(xstage0 + i * 256),
                16, 0, 0);
        }
    }

    // ---- (C) tile1 FULL x DMA -> xstage1 (32 x 16B; 2 rows per instr) ----
    // lane l of instr i: row r = 2i + (l>>5), slot s = l&31, src chunk j = s ^ (r&7)
    {
        const int rr = lane >> 5;
        const int s  = lane & 31;
#pragma unroll
        for (int i = 0; i < 32; ++i) {
            const int r = i * 2 + rr;
            const int j = s ^ (r & 7);
            const float* src = x + (row1 + r) * 128 + j * 4;
            __builtin_amdgcn_global_load_lds(
                (const __attribute__((address_space(1))) void*)src,
                (__attribute__((address_space(3))) void*)(xstage1 + i * 256),
                16, 0, 0);
        }
    }

    // ---- (D) tile0 passthrough + B0 (waits only on xm — older than the DMAs) ----
    half8 B0[2][4];
#pragma unroll
    for (int nt = 0; nt < 4; ++nt) {
#pragma unroll
        for (int kt = 0; kt < 4; ++kt)
            *(f32x4*)(yr0 + nt * 2048 + kt * 16) = xm[nt][kt];
        B0[0][nt] = cvt_frag<false>(xm[nt][0], xm[nt][1]);
        B0[1][nt] = cvt_frag<false>(xm[nt][2], xm[nt][3]);
    }

    // ---- (E) tile0 MLPs (tile1's 32 KB DMA stays in flight under this) ----
    f32x4 acc[4][4];
    half4 shp[4][4];
    run_mlps(wf, cbh, cbo, sbh, sbo, lane, g4, B0, shp, acc);

    // ---- (F) drain; tile0 epilogue from xstage0 ----
    asm volatile("s_waitcnt vmcnt(0)" ::: "memory");
    __builtin_amdgcn_sched_barrier(0);
    epilogue(acc, shp, xstage0, 64, 0, yr0, logdet, row0, lane, c, g);

    // ---- (G) tile1: x_masked from LDS (zero HBM latency), passthrough + B0 ----
    float* yr1 = y + (row1 + c) * 128 + g4;
#pragma unroll
    for (int nt = 0; nt < 4; ++nt) {
        const int r = nt * 16 + c;
        f32x4 v[4];
#pragma unroll
        for (int kt = 0; kt < 4; ++kt) {
            const int j = ((kt * 4 + g) ^ (r & 7)) * 4;
            v[kt] = *(const f32x4*)(xstage1 + r * 128 + j);
            *(f32x4*)(yr1 + nt * 2048 + kt * 16) = v[kt];
        }
        B0[0][nt] = cvt_frag<false>(v[0], v[1]);
        B0[1][nt] = cvt_frag<false>(v[2], v[3]);
    }

    // ---- (H) tile1 MLPs ----
    run_mlps(wf, cbh, cbo, sbh, sbo, lane, g4, B0, shp, acc);

    // ---- (I) tile1 epilogue from xstage1's x_t half ----
    epilogue(acc, shp, xstage1, 128, 64, yr1, logdet, row1, lane, c, g);
}

extern "C" void kernel_launch(void* const* d_in, const int* in_sizes, int n_in,
                              void* d_out, int out_size, void* d_ws, size_t ws_size,
                              hipStream_t stream) {
    const float* x   = (const float*)d_in[0];
    const float* cWh = (const float*)d_in[1];
    const float* cbh = (const float*)d_in[2];
    const float* cWo = (const float*)d_in[3];
    const float* cbo = (const float*)d_in[4];
    const float* sWh = (const float*)d_in[5];
    const float* sbh = (const float*)d_in[6];
    const float* sWo = (const float*)d_in[7];
    const float* sbo = (const float*)d_in[8];

    const int B = in_sizes[0] / 128;  // 524288

    _Float16* wf = (_Float16*)d_ws;  // 8 layers * 2 kp * 2 planes * 2048 halves = 128 KB

    prep_weights<<<128, 256, 0, stream>>>(cWh, cWo, sWh, sWo, wf);

    float* y = (float*)d_out;
    float* logdet = y + (size_t)B * 128;
    coupling_main<<<B / 128, 64, 0, stream>>>(x, cbh, cbo, sbh, sbo, wf, y, logdet);
}

// Round 20
// 166.411 us; speedup vs baseline: 1.4175x; 1.4175x over previous
//
#include <hip/hip_runtime.h>
#include <cstdint>

typedef __attribute__((ext_vector_type(8))) _Float16 half8;
typedef __attribute__((ext_vector_type(4))) _Float16 half4;
typedef __attribute__((ext_vector_type(4))) float f32x4;

// ---------------- weight prep: fp32 W -> permuted-K fp16 hi/lo A-fragments ----------------
// k-slot (g,e) of k-step kp holds feature f = (2kp + (e>>2))*16 + 4g + (e&3).
// Layout: wf[(Lid*2+kp)*2 + plane][lane][mt][e]  (2048 halves per plane-frag)
__global__ void prep_weights(const float* __restrict__ cWh, const float* __restrict__ cWo,
                             const float* __restrict__ sWh, const float* __restrict__ sWo,
                             _Float16* __restrict__ wf) {
    int t = blockIdx.x * 256 + threadIdx.x;  // 0..32767
    int e    = t & 7;
    int mt   = (t >> 3) & 3;
    int lane = (t >> 5) & 63;
    int kp   = (t >> 11) & 1;
    int L    = (t >> 12) & 7;
    const float* src = (L < 3)  ? cWh + L * 4096
                     : (L == 3) ? cWo
                     : (L < 7)  ? sWh + (L - 4) * 4096
                     :            sWo;
    int m = mt * 16 + (lane & 15);
    int k = (2 * kp + (e >> 2)) * 16 + 4 * (lane >> 4) + (e & 3);
    float w = src[m * 64 + k];
    _Float16 hi = (_Float16)w;            // RTNE hardware cvt
    _Float16 lo = (_Float16)(w - (float)hi);
    int off = lane * 32 + mt * 8 + e;
    int fi = (L * 2 + kp) * 2;
    wf[fi * 2048 + off]       = hi;
    wf[(fi + 1) * 2048 + off] = lo;
}

// build one fp16 B-fragment from two f32x4 acc tiles (k-tiles 2kp, 2kp+1), with optional relu
template<bool RELU>
__device__ __forceinline__ half8 cvt_frag(f32x4 a, f32x4 b) {
    half8 r;
#pragma unroll
    for (int i = 0; i < 4; ++i) {
        float va = RELU ? fmaxf(a[i], 0.f) : a[i];
        float vb = RELU ? fmaxf(b[i], 0.f) : b[i];
        r[i]     = (_Float16)va;
        r[i + 4] = (_Float16)vb;
    }
    return r;
}

// ---------------- one MLP layer (64 samples/wave): 2-term weights x 1-term activations ----------------
__device__ __forceinline__ void run_layer(const _Float16* __restrict__ wf, int Lid,
                                          const float* __restrict__ bias, int lane, int g4,
                                          const half8 B[2][4], f32x4 acc[4][4]) {
#pragma unroll
    for (int mt = 0; mt < 4; ++mt) {
        f32x4 bb = *(const f32x4*)(bias + mt * 16 + g4);
#pragma unroll
        for (int nt = 0; nt < 4; ++nt) acc[mt][nt] = bb;
    }
#pragma unroll
    for (int kp = 0; kp < 2; ++kp) {
        half8 Ah[4], Al[4];
        const _Float16* p = wf + (Lid * 2 + kp) * 4096 + lane * 32;
#pragma unroll
        for (int mt = 0; mt < 4; ++mt) {
            Ah[mt] = *(const half8*)(p + mt * 8);
            Al[mt] = *(const half8*)(p + 2048 + mt * 8);
        }
#pragma unroll
        for (int nt = 0; nt < 4; ++nt)
#pragma unroll
            for (int mt = 0; mt < 4; ++mt) {
                acc[mt][nt] = __builtin_amdgcn_mfma_f32_16x16x32_f16(Ah[mt], B[kp][nt], acc[mt][nt], 0, 0, 0);
                acc[mt][nt] = __builtin_amdgcn_mfma_f32_16x16x32_f16(Al[mt], B[kp][nt], acc[mt][nt], 0, 0, 0);
            }
    }
}

__device__ __forceinline__ void acc_to_B_relu(const f32x4 acc[4][4], half8 B[2][4]) {
#pragma unroll
    for (int kp = 0; kp < 2; ++kp)
#pragma unroll
        for (int nt = 0; nt < 4; ++nt)
            B[kp][nt] = cvt_frag<true>(acc[2 * kp][nt], acc[2 * kp + 1][nt]);
}

// ---------------- main: 2 waves/block, each wave = 64 rows; x_t DMA'd to its LDS slice ----------------
// Per-wave logic identical to the proven R18 kernel; 128-thread blocks exist purely to
// sidestep the ~7 blocks/CU dispatcher cap observed with 1-wave blocks (LDS math then
// allows 5 blocks x 2 waves = 10 waves/CU).
__global__ __launch_bounds__(128, 2)
void coupling_main(const float* __restrict__ x,
                   const float* __restrict__ cbh, const float* __restrict__ cbo,
                   const float* __restrict__ sbh, const float* __restrict__ sbo,
                   const _Float16* __restrict__ wf,
                   float* __restrict__ y, float* __restrict__ logdet) {
    __shared__ float xstage2[2][4096];  // 2 x 16 KB: per-wave x_t[64][64] (chunk-swizzled)
    const int lane = threadIdx.x & 63;
    const int wid = threadIdx.x >> 6;
    float* xstage = xstage2[wid];
    const int c = lane & 15;
    const int g = lane >> 4;
    const int g4 = g * 4;
    const long row0 = (long)blockIdx.x * 128 + wid * 64;
    const float* xr = x + (row0 + c) * 128 + g4;
    float* yr = y + (row0 + c) * 128 + g4;

    // (1) x_masked register loads (16 x 16B) — issued first so their waitcnt
    //     leaves the DMA below still outstanding
    f32x4 xm[4][4];
#pragma unroll
    for (int nt = 0; nt < 4; ++nt)
#pragma unroll
        for (int kt = 0; kt < 4; ++kt)
            xm[nt][kt] = *(const f32x4*)(xr + nt * 2048 + kt * 16);

    // (2) DMA x_transform -> LDS: 16 x global_load_lds_dwordx4 (no VGPR destination).
    //     Instr i stages rows [4i, 4i+4): lane l -> row 4i + (l>>4), dest slot l&15,
    //     global chunk j = (l&15) ^ (row&7).
    {
        const int rr = lane >> 4;
        const int s  = lane & 15;
#pragma unroll
        for (int i = 0; i < 16; ++i) {
            const int r = i * 4 + rr;
            const int j = s ^ (r & 7);
            const float* src = x + (row0 + r) * 128 + 64 + j * 4;
            __builtin_amdgcn_global_load_lds(
                (const __attribute__((address_space(1))) void*)src,
                (__attribute__((address_space(3))) void*)(xstage + i * 256),
                16, 0, 0);
        }
    }

    // (3) passthrough y[:, :64] + build B0 frags (parked, 32 regs); plain cached stores
    half8 B0[2][4];
#pragma unroll
    for (int nt = 0; nt < 4; ++nt) {
#pragma unroll
        for (int kt = 0; kt < 4; ++kt)
            *(f32x4*)(yr + nt * 2048 + kt * 16) = xm[nt][kt];
        B0[0][nt] = cvt_frag<false>(xm[nt][0], xm[nt][1]);
        B0[1][nt] = cvt_frag<false>(xm[nt][2], xm[nt][3]);
    }

    f32x4 acc[4][4];
    half8 B[2][4];

    // cond MLP (ids 0..3) -> shift (parked as fp16, 32 regs)
    run_layer(wf, 0, cbh,       lane, g4, B0, acc);
    acc_to_B_relu(acc, B);
    run_layer(wf, 1, cbh + 64,  lane, g4, B, acc);
    acc_to_B_relu(acc, B);
    run_layer(wf, 2, cbh + 128, lane, g4, B, acc);
    acc_to_B_relu(acc, B);
    run_layer(wf, 3, cbo,       lane, g4, B, acc);
    half4 shp[4][4];
#pragma unroll
    for (int mt = 0; mt < 4; ++mt)
#pragma unroll
        for (int nt = 0; nt < 4; ++nt) {
            half4 s;
#pragma unroll
            for (int i = 0; i < 4; ++i) s[i] = (_Float16)acc[mt][nt][i];
            shp[mt][nt] = s;
        }

    // scale MLP (ids 4..7) -> log_scale in acc
    run_layer(wf, 4, sbh,       lane, g4, B0, acc);
    acc_to_B_relu(acc, B);
    run_layer(wf, 5, sbh + 64,  lane, g4, B, acc);
    acc_to_B_relu(acc, B);
    run_layer(wf, 6, sbh + 128, lane, g4, B, acc);
    acc_to_B_relu(acc, B);
    run_layer(wf, 7, sbo,       lane, g4, B, acc);

    // (4) drain the DMA (completed long ago, during the MLP), then epilogue from LDS
    asm volatile("s_waitcnt vmcnt(0)" ::: "memory");
    __builtin_amdgcn_sched_barrier(0);

    float pld0 = 0.f, pld1 = 0.f, pld2 = 0.f, pld3 = 0.f;
#pragma unroll
    for (int nt = 0; nt < 4; ++nt) {
        float psum = 0.f;
        const int r = nt * 16 + c;
#pragma unroll
        for (int mt = 0; mt < 4; ++mt) {
            f32x4 ls = acc[mt][nt];
            psum += ls[0] + ls[1] + ls[2] + ls[3];
            const int j = (mt * 4 + g) ^ (r & 7);
            f32x4 xt = *(const f32x4*)(xstage + r * 64 + j * 4);
            half4 sp = shp[mt][nt];
            f32x4 o;
#pragma unroll
            for (int i = 0; i < 4; ++i) {
                float cl = fminf(fmaxf(ls[i], -5.f), 3.f);
                o[i] = xt[i] * __expf(cl) + (float)sp[i];
            }
            *(f32x4*)(yr + nt * 2048 + 64 + mt * 16) = o;
        }
        if (nt == 0) pld0 = psum; else if (nt == 1) pld1 = psum;
        else if (nt == 2) pld2 = psum; else pld3 = psum;
    }
#pragma unroll
    for (int nt = 0; nt < 4; ++nt) {
        float v = (nt == 0) ? pld0 : (nt == 1) ? pld1 : (nt == 2) ? pld2 : pld3;
        v += __shfl_xor(v, 16);
        v += __shfl_xor(v, 32);
        if ((lane >> 4) == 0) logdet[row0 + nt * 16 + c] = v;
    }
}

extern "C" void kernel_launch(void* const* d_in, const int* in_sizes, int n_in,
                              void* d_out, int out_size, void* d_ws, size_t ws_size,
                              hipStream_t stream) {
    const float* x   = (const float*)d_in[0];
    const float* cWh = (const float*)d_in[1];
    const float* cbh = (const float*)d_in[2];
    const float* cWo = (const float*)d_in[3];
    const float* cbo = (const float*)d_in[4];
    const float* sWh = (const float*)d_in[5];
    const float* sbh = (const float*)d_in[6];
    const float* sWo = (const float*)d_in[7];
    const float* sbo = (const float*)d_in[8];

    const int B = in_sizes[0] / 128;  // 524288

    _Float16* wf = (_Float16*)d_ws;  // 8 layers * 2 kp * 2 planes * 2048 halves = 128 KB

    prep_weights<<<128, 256, 0, stream>>>(cWh, cWo, sWh, sWo, wf);

    float* y = (float*)d_out;
    float* logdet = y + (size_t)B * 128;
    coupling_main<<<B / 128, 128, 0, stream>>>(x, cbh, cbo, sbh, sbo, wf, y, logdet);
}